// Round 2
// baseline (78.046 us; speedup 1.0000x reference)
//
#include <hip/hip_runtime.h>

// SimilarityBasedFilter: bilateral depth filter, 5x5 window, zero padding.
// out = sum(v*w) / (sum(w)+1e-6), w = exp(-(v-center)^2 / (2*0.1^2))
// Each thread computes 4 horizontal pixels from an LDS tile.
// LDS row stride 72 floats (288 B) keeps per-thread 8-float row segments
// 16B-aligned -> two ds_read_b128 per row per thread.

#define KW 5
#define PADR 2
#define TX 16        // threads in x, each covers 4 pixels -> 64-wide tile
#define TY 16        // threads in y -> 16-tall tile
#define TILE_W 64
#define TILE_H 16
#define LW 72                    // padded row stride (floats), 288 B
#define LH (TILE_H + 2 * PADR)   // 20

__global__ __launch_bounds__(TX * TY) void sim_filter_kernel(
    const float* __restrict__ depth, float* __restrict__ out,
    int H, int W) {
    __shared__ float tile[LH * LW];

    const int tx = threadIdx.x;            // 0..15
    const int ty = threadIdx.y;            // 0..15
    const int tid = ty * TX + tx;          // 0..255
    const int bx0 = blockIdx.x * TILE_W;   // tile origin x
    const int by0 = blockIdx.y * TILE_H;   // tile origin y
    const int b = blockIdx.z;

    const float* src = depth + (size_t)b * H * W;

    // cooperative halo load (zero padding); cols 68..71 are alignment pad
    for (int i = tid; i < LH * LW; i += TX * TY) {
        int ly = i / LW;
        int lx = i - ly * LW;
        int gy = by0 + ly - PADR;
        int gx = bx0 + lx - PADR;
        float v = 0.0f;
        if (gy >= 0 && gy < H && gx >= 0 && gx < W)
            v = src[gy * W + gx];
        tile[i] = v;
    }
    __syncthreads();

    // load 5 rows x 8 floats (two aligned float4 each)
    float r[KW][8];
#pragma unroll
    for (int dy = 0; dy < KW; ++dy) {
        const float4* p = (const float4*)&tile[(ty + dy) * LW + tx * 4];
        float4 a = p[0];
        float4 c = p[1];
        r[dy][0] = a.x; r[dy][1] = a.y; r[dy][2] = a.z; r[dy][3] = a.w;
        r[dy][4] = c.x; r[dy][5] = c.y; r[dy][6] = c.z; r[dy][7] = c.w;
    }

    // exp(-50*d^2) = exp2(d^2 * -50*log2(e))
    const float c2 = -72.13475204444817f;

    float wsum[4] = {0.f, 0.f, 0.f, 0.f};
    float wtot[4] = {0.f, 0.f, 0.f, 0.f};
#pragma unroll
    for (int dy = 0; dy < KW; ++dy) {
#pragma unroll
        for (int j = 0; j < 4; ++j) {
            const float center = r[2][j + 2];
#pragma unroll
            for (int dx = 0; dx < KW; ++dx) {
                float v = r[dy][j + dx];
                float d = v - center;
                float w = exp2f(d * d * c2);
                wsum[j] = fmaf(v, w, wsum[j]);
                wtot[j] += w;
            }
        }
    }

    float4 o;
    o.x = wsum[0] / (wtot[0] + 1e-6f);
    o.y = wsum[1] / (wtot[1] + 1e-6f);
    o.z = wsum[2] / (wtot[2] + 1e-6f);
    o.w = wsum[3] / (wtot[3] + 1e-6f);

    const int gy = by0 + ty;
    const int gx = bx0 + tx * 4;
    *(float4*)&out[((size_t)b * H + gy) * W + gx] = o;
}

extern "C" void kernel_launch(void* const* d_in, const int* in_sizes, int n_in,
                              void* d_out, int out_size, void* d_ws, size_t ws_size,
                              hipStream_t stream) {
    const float* depth = (const float*)d_in[0];
    float* out = (float*)d_out;

    const int H = 512, W = 512, Bn = 8;
    dim3 block(TX, TY);
    dim3 grid(W / TILE_W, H / TILE_H, Bn);
    sim_filter_kernel<<<grid, block, 0, stream>>>(depth, out, H, W);
}